// Round 9
// baseline (38354.340 us; speedup 1.0000x reference)
//
#include <hip/hip_runtime.h>
#include <math.h>

// Disable FP contraction file-wide so every rounding step is the one we wrote;
// fmas are explicit via fmaf() where we want to mimic the XLA/Eigen dot chain.
#pragma clang fp contract(off)

#define VOCAB 4096
#define NPTS  32768          // 4 * 8192
#define NELEM 98304          // NPTS * 3
#define G     32
#define CELLS (G * G * G)    // 32768
#define QL    8              // lanes cooperating per point
#define ABLOCK 512
#define PTS_PER_BLOCK (ABLOCK / QL)   // 64 points/block -> 512 blocks
#define DELTA 1e-2f          // >> max fp32 rounding error of the distance expr

// ---------------------------------------------------------------------------
// Kernel 0: grid build (single 1024-thread block).
//  P0 uniform bounds over feats+embed (grid covers every query point, so the
//     stopping bound's "point inside visited box" invariant always holds)
//  P1 zero 32k-cell histogram   P2 code->cell + atomic hist
//  P3 exclusive scan (per-thread 32 serial + block Hillis-Steele)
//  P4 scatter codes into CSR order (slot via atomicAdd cursor); the float4
//     stores (e0,e1,e2, bitcast(original index)) -- evaluation recomputes
//     esq with the reference association, so values stay bit-exact.
//  P5 cstart[c+1] = end-of-cell-c (cursor after scatter), cstart[0]=0.
// Atomic-result reads use atomicAdd(p,0) (L2 read) to dodge stale-L1 risk.
// CSR within-cell order is atomic-arrival (nondeterministic) -- harmless:
// the assign kernel's (d, idx) lexicographic compare is order-independent.
// ---------------------------------------------------------------------------
__global__ __launch_bounds__(1024) void grid_build(
    const float* __restrict__ feats, const float* __restrict__ embed,
    float4* __restrict__ scodes, int* __restrict__ cur, int* __restrict__ cstart,
    float* __restrict__ gb)
{
  __shared__ float sred[16][2];
  __shared__ float sb[3];          // lo, h, invh
  __shared__ int   sscan[1024];
  const int tid = threadIdx.x;
  const int lane = tid & 63, wv = tid >> 6;

  // P0: uniform min/max over feats (24576 float4) + embed (3072 float4)
  float mn = INFINITY, mx = -INFINITY;
  const float4* f4 = (const float4*)feats;
  for (int i = tid; i < NELEM / 4; i += 1024) {
    float4 v = f4[i];
    mn = fminf(mn, fminf(fminf(v.x, v.y), fminf(v.z, v.w)));
    mx = fmaxf(mx, fmaxf(fmaxf(v.x, v.y), fmaxf(v.z, v.w)));
  }
  const float4* e4 = (const float4*)embed;
  for (int i = tid; i < (VOCAB * 3) / 4; i += 1024) {
    float4 v = e4[i];
    mn = fminf(mn, fminf(fminf(v.x, v.y), fminf(v.z, v.w)));
    mx = fmaxf(mx, fmaxf(fmaxf(v.x, v.y), fmaxf(v.z, v.w)));
  }
  #pragma unroll
  for (int m = 1; m <= 32; m <<= 1) {
    mn = fminf(mn, __shfl_xor(mn, m, 64));
    mx = fmaxf(mx, __shfl_xor(mx, m, 64));
  }
  if (lane == 0) { sred[wv][0] = mn; sred[wv][1] = mx; }
  __syncthreads();
  if (tid == 0) {
    float a = INFINITY, b = -INFINITY;
    for (int w = 0; w < 16; ++w) { a = fminf(a, sred[w][0]); b = fmaxf(b, sred[w][1]); }
    float lo = a - 1e-3f;
    // inflate h so lo + 32h strictly covers the max value (floor stays <= 31)
    float h = (b + 1e-3f - lo) * 0.03125f * (1.0f + 4e-6f);
    sb[0] = lo; sb[1] = h; sb[2] = 1.0f / h;
    gb[0] = lo; gb[1] = h; gb[2] = sb[2];
  }
  __syncthreads();
  const float lo = sb[0], ih = sb[2];

  // P1: zero histogram
  for (int i = tid; i < CELLS; i += 1024) cur[i] = 0;
  __threadfence();
  __syncthreads();

  // P2: cell per code + histogram
  int   mycell[4];
  float me[4][3];
  #pragma unroll
  for (int k = 0; k < 4; ++k) {
    int c = k * 1024 + tid;
    float e0 = embed[3 * c + 0], e1 = embed[3 * c + 1], e2 = embed[3 * c + 2];
    me[k][0] = e0; me[k][1] = e1; me[k][2] = e2;
    int cx = min(max((int)floorf((e0 - lo) * ih), 0), G - 1);
    int cy = min(max((int)floorf((e1 - lo) * ih), 0), G - 1);
    int cz = min(max((int)floorf((e2 - lo) * ih), 0), G - 1);
    mycell[k] = (cz * G + cy) * G + cx;
    atomicAdd(&cur[mycell[k]], 1);
  }
  __threadfence();
  __syncthreads();

  // P3: exclusive scan of the 32768 counts
  const int base = tid * 32;
  int loc[32];
  int s = 0;
  #pragma unroll
  for (int j = 0; j < 32; ++j) {
    int t = atomicAdd(&cur[base + j], 0);   // L2-coherent read of atomic results
    loc[j] = s;
    s += t;
  }
  sscan[tid] = s;
  __syncthreads();
  for (int off = 1; off < 1024; off <<= 1) {
    int t2 = (tid >= off) ? sscan[tid - off] : 0;
    __syncthreads();
    sscan[tid] += t2;
    __syncthreads();
  }
  const int excl = sscan[tid] - s;
  #pragma unroll
  for (int j = 0; j < 32; ++j) cur[base + j] = loc[j] + excl;
  __threadfence();
  __syncthreads();

  // P4: scatter codes (slot = cursor++)
  #pragma unroll
  for (int k = 0; k < 4; ++k) {
    int slot = atomicAdd(&cur[mycell[k]], 1);
    scodes[slot] = make_float4(me[k][0], me[k][1], me[k][2],
                               __int_as_float(k * 1024 + tid));
  }
  __threadfence();
  __syncthreads();

  // P5: cstart from post-scatter cursors (cur[c] == end of cell c)
  if (tid == 0) cstart[0] = 0;
  for (int i = tid; i < CELLS; i += 1024) cstart[i + 1] = atomicAdd(&cur[i], 0);
}

// ---------------------------------------------------------------------------
// Kernel 1: pruned nearest-code assignment + quant_st + idx + scatter + SSE.
//
// 8 lanes per point (4096 waves = 16/CU). Chebyshev rings around the point's
// cell; ring r enumerates the (2r+1)^3 box shell (full box at r=1), positions
// dealt to lanes round-robin by linear position (incremental carry stepping,
// no divides). Stop when the visited clamped box's boundary distance b gives
// b*b > best + DELTA (any unexamined code then has reference-distance > best
// strictly -- argmin and all ties already examined), or the box covers the
// grid. Distance expression is bit-identical to the verified rounds 1-8;
// (d, idx) lexicographic update reproduces argmin first-min semantics
// independent of examination order.
// ---------------------------------------------------------------------------
__global__ __launch_bounds__(ABLOCK) void vq_assign(
    const float* __restrict__ feats, const float* __restrict__ embed,
    const float4* __restrict__ scodes, const int* __restrict__ cstart,
    const float* __restrict__ gb,
    float* __restrict__ out_quant, float* __restrict__ out_idx,
    float* __restrict__ counts, float* __restrict__ sums,
    float* __restrict__ sse)
{
  const int tid  = threadIdx.x;
  const int octl = tid & (QL - 1);
  const int p    = blockIdx.x * PTS_PER_BLOCK + (tid >> 3);

  const float lo = gb[0], h = gb[1], ih = gb[2];
  const float x0 = feats[3 * p + 0];
  const float x1 = feats[3 * p + 1];
  const float x2 = feats[3 * p + 2];
  const float xsq = (x0 * x0 + x1 * x1) + x2 * x2;
  const int cx = min(max((int)floorf((x0 - lo) * ih), 0), G - 1);
  const int cy = min(max((int)floorf((x1 - lo) * ih), 0), G - 1);
  const int cz = min(max((int)floorf((x2 - lo) * ih), 0), G - 1);

  float best = INFINITY;
  int   bidx = 0x7fffffff;
  bool  done = false;

  for (int r = 1; r <= 36; ++r) {
    if (!done) {
      const int side  = 2 * r + 1;
      const int total = side * side * side;
      // decompose linear position octl into (dx,dy,dz), dx fastest
      int dz = -r, dy = -r, dx = -r + octl;
      while (dx > r) { dx -= side; ++dy; }
      while (dy > r) { dy -= side; ++dz; }
      for (int jj = octl; jj < total; jj += QL) {
        int adx = dx < 0 ? -dx : dx;
        int ady = dy < 0 ? -dy : dy;
        int adz = dz < 0 ? -dz : dz;
        if (r == 1 || max(max(adx, ady), adz) == r) {   // shell (r>1) / full box (r==1)
          int ix = cx + dx, iy = cy + dy, iz = cz + dz;
          if (((unsigned)ix < G) && ((unsigned)iy < G) && ((unsigned)iz < G)) {
            int cell = (iz * G + iy) * G + ix;
            int s = cstart[cell], s1 = cstart[cell + 1];
            for (; s < s1; ++s) {
              float4 e = scodes[s];
              // verified bit-exact distance: fma-chained dot, (xsq-2dot)+esq
              float dot = fmaf(x2, e.z, fmaf(x1, e.y, x0 * e.x));
              float esq = (e.x * e.x + e.y * e.y) + e.z * e.z;
              float d = (xsq - 2.0f * dot) + esq;
              int oi = __float_as_int(e.w);
              if (d < best || (d == best && oi < bidx)) { best = d; bidx = oi; }
            }
          }
        }
        dx += QL;
        while (dx > r) { dx -= side; ++dy; }
        while (dy > r) { dy -= side; ++dz; }
      }
      // combine (d, idx) across the point's 8 lanes
      #pragma unroll
      for (int m = 1; m <= 4; m <<= 1) {
        float od = __shfl_xor(best, m, 64);
        int   oi = __shfl_xor(bidx, m, 64);
        if (od < best || (od == best && oi < bidx)) { best = od; bidx = oi; }
      }
      // stopping bound: distance from point to visited-box boundary
      float bxlo0 = lo + h * (float)max(cx - r, 0);
      float bxhi0 = lo + h * (float)(min(cx + r, G - 1) + 1);
      float bxlo1 = lo + h * (float)max(cy - r, 0);
      float bxhi1 = lo + h * (float)(min(cy + r, G - 1) + 1);
      float bxlo2 = lo + h * (float)max(cz - r, 0);
      float bxhi2 = lo + h * (float)(min(cz + r, G - 1) + 1);
      float b = fminf(fminf(x0 - bxlo0, bxhi0 - x0),
               fminf(fminf(x1 - bxlo1, bxhi1 - x1),
                     fminf(x2 - bxlo2, bxhi2 - x2)));
      b = fmaxf(b, 0.0f);
      bool full = (cx - r <= 0) && (cx + r >= G - 1) &&
                  (cy - r <= 0) && (cy + r >= G - 1) &&
                  (cz - r <= 0) && (cz + r >= G - 1);
      done = full || (b * b > best + DELTA);
    }
    if (__all(done)) break;
  }

  // epilogue: one lane per point
  float l = 0.0f;
  if (octl == 0) {
    const float q0 = embed[3 * bidx + 0];   // original values, bit-exact
    const float q1 = embed[3 * bidx + 1];
    const float q2 = embed[3 * bidx + 2];
    // quant_st = feats + (quant - feats), exactly as the reference evaluates
    out_quant[3 * p + 0] = x0 + (q0 - x0);
    out_quant[3 * p + 1] = x1 + (q1 - x1);
    out_quant[3 * p + 2] = x2 + (q2 - x2);
    out_idx[p] = (float)bidx;
    atomicAdd(&counts[bidx], 1.0f);
    atomicAdd(&sums[3 * bidx + 0], x0);
    atomicAdd(&sums[3 * bidx + 1], x1);
    atomicAdd(&sums[3 * bidx + 2], x2);
    float d0 = q0 - x0, d1 = q1 - x1, d2 = q2 - x2;
    l = (d0 * d0 + d1 * d1) + d2 * d2;
  }
  #pragma unroll
  for (int m = 1; m <= 32; m <<= 1) l += __shfl_xor(l, m, 64);
  if ((tid & 63) == 0) atomicAdd(sse, l);
}

// ---------------------------------------------------------------------------
// Kernel 2: EMA update, global n-reduction, normalized embed, loss finalize.
// (unchanged from the verified rounds)
// ---------------------------------------------------------------------------
__global__ __launch_bounds__(1024) void vq_ema(
    const float* __restrict__ counts, const float* __restrict__ sums,
    const float* __restrict__ sse,
    const float* __restrict__ ema_cs, const float* __restrict__ ema_w,
    float* __restrict__ out_loss, float* __restrict__ out_ncs,
    float* __restrict__ out_nw, float* __restrict__ out_nemb)
{
  __shared__ float part[16];
  const int tid = threadIdx.x;
  const float DEC = 0.99f;
  const float OMD = (float)(1.0 - 0.99);
  const float EPS = 1e-5f;

  float ncs[4];
  float nw[12];
  float nsum = 0.0f;

  #pragma unroll
  for (int k = 0; k < 4; ++k) {
    int v = k * 1024 + tid;
    float t = DEC * ema_cs[v] + OMD * counts[v];
    ncs[k] = t;
    out_ncs[v] = t;
    nsum += t;
    #pragma unroll
    for (int d = 0; d < 3; ++d) {
      float w = DEC * ema_w[3 * v + d] + OMD * sums[3 * v + d];
      nw[3 * k + d] = w;
      out_nw[3 * v + d] = w;
    }
  }

  #pragma unroll
  for (int m = 1; m <= 32; m <<= 1) nsum += __shfl_xor(nsum, m, 64);
  if ((tid & 63) == 0) part[tid >> 6] = nsum;
  __syncthreads();

  float n = 0.0f;
  #pragma unroll
  for (int i = 0; i < 16; ++i) n += part[i];
  const float denom = n + (float)VOCAB * EPS;

  #pragma unroll
  for (int k = 0; k < 4; ++k) {
    int v = k * 1024 + tid;
    float cs = (ncs[k] + EPS) / denom * n;
    #pragma unroll
    for (int d = 0; d < 3; ++d)
      out_nemb[3 * v + d] = nw[3 * k + d] / cs;
  }

  if (tid == 0) {
    float m = sse[0] / (float)NELEM;
    out_loss[0] = m + 0.25f * m;   // mean((q-f)^2) + 0.25*mean((f-q)^2)
  }
}

// ---------------------------------------------------------------------------
extern "C" void kernel_launch(void* const* d_in, const int* in_sizes, int n_in,
                              void* d_out, int out_size, void* d_ws, size_t ws_size,
                              hipStream_t stream) {
  const float* feats  = (const float*)d_in[0];   // (4,8192,3)
  const float* embed  = (const float*)d_in[1];   // (4096,3)
  const float* ema_cs = (const float*)d_in[2];   // (4096,)
  const float* ema_w  = (const float*)d_in[3];   // (4096,3)

  float* out      = (float*)d_out;
  float* o_quant  = out;                       // 98304
  float* o_idx    = out + 98304;               // 32768
  float* o_loss   = out + 131072;              // 1
  float* o_ncs    = out + 131073;              // 4096
  float* o_nw     = out + 135169;              // 12288
  float* o_nemb   = out + 147457;              // 12288

  float*  ws_f      = (float*)d_ws;
  float*  ws_counts = ws_f;                    // 4096
  float*  ws_sums   = ws_f + 4096;             // 12288
  float*  ws_sse    = ws_f + 16384;            // 1
  float4* ws_scodes = (float4*)(ws_f + 16388); // 4096 float4 (byte off 65552, 16B-aligned)
  float*  ws_gb     = ws_f + 32772;            // 3 floats (lo, h, invh)
  int*    ws_cur    = (int*)(ws_f + 32784);    // 32768 ints
  int*    ws_cstart = (int*)(ws_f + 65552);    // 32769 ints

  hipMemsetAsync(d_ws, 0, (size_t)16385 * sizeof(float), stream);

  grid_build<<<1, 1024, 0, stream>>>(feats, embed, ws_scodes, ws_cur, ws_cstart, ws_gb);

  vq_assign<<<NPTS / PTS_PER_BLOCK, ABLOCK, 0, stream>>>(
      feats, embed, ws_scodes, ws_cstart, ws_gb,
      o_quant, o_idx, ws_counts, ws_sums, ws_sse);

  vq_ema<<<1, 1024, 0, stream>>>(
      ws_counts, ws_sums, ws_sse, ema_cs, ema_w,
      o_loss, o_ncs, o_nw, o_nemb);
}

// Round 10
// 55.676 us; speedup vs baseline: 688.8828x; 688.8828x over previous
//
#include <hip/hip_runtime.h>
#include <math.h>

// Disable FP contraction file-wide so every rounding step is the one we wrote;
// fmas are explicit (packed fma asm / fmaf) matching the XLA/Eigen dot chain.
#pragma clang fp contract(off)

#define VOCAB 4096
#define NPTS  32768          // 4 * 8192
#define NELEM 98304          // NPTS * 3
#define BLOCK 1024
#define NWAVE 16                     // waves per block
#define CPW   (VOCAB / NWAVE)        // 256 codes scanned per wave
#define PAIRS_PW (CPW / 2)           // 128 code-pairs per wave
#define PPL   2                      // points per lane
#define PTS_PER_BLOCK (64 * PPL)     // 128 points per block -> 256 blocks

typedef float v2f __attribute__((ext_vector_type(2)));

// ---------------------------------------------------------------------------
// Kernel 0: pack the codebook in PAIR layout with NEGATED, PRE-DOUBLED
// components + esq:
//   pc[2m]   = (-2e0_k, -2e0_k1, -2e1_k, -2e1_k1)    (codes k=2m, k1=2m+1)
//   pc[2m+1] = (-2e2_k, -2e2_k1,  esq_k,  esq_k1)
// Negation and x2 are exact; IEEE rounding is sign-symmetric, so the packed
// mul/fma chain on these values is bit-exactly -2*dot of the reference chain.
// esq keeps the reference association (e0*e0 + e1*e1) + e2*e2.
// ---------------------------------------------------------------------------
__global__ __launch_bounds__(1024) void vq_prep(
    const float* __restrict__ embed, float4* __restrict__ pc)
{
  const int m = blockIdx.x * 1024 + threadIdx.x;   // pair id, [0, 2048)
  const int c0 = 2 * m, c1 = 2 * m + 1;
  float a0 = embed[3 * c0 + 0], a1 = embed[3 * c0 + 1], a2 = embed[3 * c0 + 2];
  float b0 = embed[3 * c1 + 0], b1 = embed[3 * c1 + 1], b2 = embed[3 * c1 + 2];
  float esqa = (a0 * a0 + a1 * a1) + a2 * a2;
  float esqb = (b0 * b0 + b1 * b1) + b2 * b2;
  pc[2 * m + 0] = make_float4(-(a0 + a0), -(b0 + b0), -(a1 + a1), -(b1 + b1));
  pc[2 * m + 1] = make_float4(-(a2 + a2), -(b2 + b2), esqa, esqb);
}

// ---------------------------------------------------------------------------
// Kernel 1: nearest-code assignment + quant_st + idx + scatter + SSE.
//
// r4-r8 established: VALU-issue wall ~29us (17 ops/eval) over an LDS-return
// floor ~20.5us (64-lane VGPR writeback per broadcast ds_read_b128). This
// round attacks both:
//  - PACKED FP32 (v_pk_mul/fma/add_f32): 2 codes per instruction. Per pair
//    per point: 5 packed + 6 tracking = 5.5 ops/eval -> VALU ~10us. The
//    packed chain on negated pre-doubled codes gives d = (xsq + (-dot2)) +
//    esq, bit-identical per half to the verified (xsq - 2*dot) + esq.
//  - DUAL-SOURCE (r8 machinery, verified absmax 0): even pairs from LDS,
//    odd pairs via vector-global (opaque VGPR offset -> no r5 K$ path),
//    halving each return path to ~10us, overlapped with VALU.
// Four index streams per point (LDS-lo/hi, GLB-lo/hi). Streams are
// ascending; strict < keeps first occurrence; lexicographic (d, idx) merges
// across streams/waves => exact argmin first-min semantics.
// ---------------------------------------------------------------------------
#define EVALPAIR(P0, P1, C2, ST)                                              \
  {                                                                           \
    v2f A  = {(P0).x, (P0).y};                                                \
    v2f Bv = {(P0).z, (P0).w};                                                \
    v2f Cv = {(P1).x, (P1).y};                                                \
    v2f Sv = {(P1).z, (P1).w};                                                \
    _Pragma("unroll")                                                         \
    for (int s = 0; s < PPL; ++s) {                                           \
      v2f t;                                                                  \
      asm("v_pk_mul_f32 %0, %1, %2" : "=v"(t) : "v"(xp0[s]), "v"(A));         \
      asm("v_pk_fma_f32 %0, %1, %2, %0" : "+v"(t) : "v"(xp1[s]), "v"(Bv));    \
      asm("v_pk_fma_f32 %0, %1, %2, %0" : "+v"(t) : "v"(xp2[s]), "v"(Cv));    \
      asm("v_pk_add_f32 %0, %1, %0" : "+v"(t) : "v"(xpq[s]));                 \
      asm("v_pk_add_f32 %0, %1, %0" : "+v"(t) : "v"(Sv));                     \
      if (t.x < bst[ST][s])     { bst[ST][s] = t.x;     bix[ST][s] = (C2); }  \
      if (t.y < bst[(ST)+1][s]) { bst[(ST)+1][s] = t.y; bix[(ST)+1][s] = (C2) + 1; } \
    }                                                                         \
  }

__global__ __launch_bounds__(BLOCK, 4) void vq_assign(
    const float* __restrict__ feats, const float* __restrict__ embed,
    const float4* __restrict__ gpc,
    float* __restrict__ out_quant, float* __restrict__ out_idx,
    float* __restrict__ counts, float* __restrict__ sums,
    float* __restrict__ sse)
{
  extern __shared__ float4 lpc[];          // [2*VOCAB/2*2]=4096 float4, 64 KiB
  __shared__ float dbuf[NWAVE][PPL][64];   // 8 KiB
  __shared__ int   ibuf[NWAVE][PPL][64];   // 8 KiB

  const int tid  = threadIdx.x;
  const int lane = tid & 63;
  const int wv   = tid >> 6;

  // Stage pair-layout codebook into LDS (coalesced float4 copies).
  #pragma unroll
  for (int c = tid; c < 2 * (VOCAB / 2) * 2; c += BLOCK) lpc[c] = gpc[c];
  __syncthreads();

  // Lane owns points pbase+lane (slot 0) and pbase+64+lane (slot 1).
  const int pbase = blockIdx.x * PTS_PER_BLOCK;
  float px[PPL][3];
  v2f xp0[PPL], xp1[PPL], xp2[PPL], xpq[PPL];
  #pragma unroll
  for (int s = 0; s < PPL; ++s) {
    const int p = pbase + s * 64 + lane;
    float x0 = feats[3 * p + 0];
    float x1 = feats[3 * p + 1];
    float x2 = feats[3 * p + 2];
    px[s][0] = x0; px[s][1] = x1; px[s][2] = x2;
    float xsq = (x0 * x0 + x1 * x1) + x2 * x2;
    xp0[s] = (v2f){x0, x0}; xp1[s] = (v2f){x1, x1};
    xp2[s] = (v2f){x2, x2}; xpq[s] = (v2f){xsq, xsq};
  }

  // 4 streams per point: 0=LDS-lo, 1=LDS-hi, 2=GLB-lo, 3=GLB-hi
  float bst[4][PPL];
  int   bix[4][PPL];
  #pragma unroll
  for (int st = 0; st < 4; ++st)
    #pragma unroll
    for (int s = 0; s < PPL; ++s) { bst[st][s] = INFINITY; bix[st][s] = 0; }

  const int mbase = wv * PAIRS_PW;
  // Opaque VGPR zero: compiler cannot prove uniformity -> vector global
  // loads (L1/L2 path), NOT s_load through the 16KB constant cache (r5 bug).
  int vz;
  asm volatile("v_mov_b32 %0, 0" : "=v"(vz));
  const float4* gpcv = gpc + vz;

  #pragma unroll 2
  for (int j = 0; j < PAIRS_PW; j += 2) {
    const int m0 = mbase + j;        // even pair -> LDS
    const int m1 = m0 + 1;           // odd pair  -> global (L2-resident)
    float4 L0 = lpc[2 * m0 + 0];
    float4 L1 = lpc[2 * m0 + 1];
    float4 G0 = gpcv[2 * m1 + 0];
    float4 G1 = gpcv[2 * m1 + 1];
    EVALPAIR(L0, L1, 2 * m0, 0);
    EVALPAIR(G0, G1, 2 * m1, 2);
  }

  // merge the 4 streams per point (lexicographic (d, idx))
  #pragma unroll
  for (int s = 0; s < PPL; ++s) {
    float b = bst[0][s];
    int   bi = bix[0][s];
    #pragma unroll
    for (int st = 1; st < 4; ++st) {
      if (bst[st][s] < b || (bst[st][s] == b && bix[st][s] < bi)) {
        b = bst[st][s]; bi = bix[st][s];
      }
    }
    dbuf[wv][s][lane] = b;
    ibuf[wv][s][lane] = bi;
  }
  __syncthreads();

  if (wv == 0) {
    #pragma unroll
    for (int s = 0; s < PPL; ++s) {
      float b = dbuf[0][s][lane];
      int   bi = ibuf[0][s][lane];
      #pragma unroll
      for (int w = 1; w < NWAVE; ++w) {
        float od = dbuf[w][s][lane];
        int   oi = ibuf[w][s][lane];
        // lexicographic (d, idx): wave ranges ascending => first-min
        if (od < b || (od == b && oi < bi)) { b = od; bi = oi; }
      }

      const int p = pbase + s * 64 + lane;
      // winning code values straight from embed: bit-exact originals
      const float q0 = embed[3 * bi + 0];
      const float q1 = embed[3 * bi + 1];
      const float q2 = embed[3 * bi + 2];
      const float x0 = px[s][0], x1 = px[s][1], x2 = px[s][2];

      // quant_st = feats + (quant - feats), exactly as the reference does
      out_quant[3 * p + 0] = x0 + (q0 - x0);
      out_quant[3 * p + 1] = x1 + (q1 - x1);
      out_quant[3 * p + 2] = x2 + (q2 - x2);
      out_idx[p] = (float)bi;

      atomicAdd(&counts[bi], 1.0f);
      atomicAdd(&sums[3 * bi + 0], x0);
      atomicAdd(&sums[3 * bi + 1], x1);
      atomicAdd(&sums[3 * bi + 2], x2);

      float d0 = q0 - x0, d1 = q1 - x1, d2 = q2 - x2;
      float l = (d0 * d0 + d1 * d1) + d2 * d2;
      #pragma unroll
      for (int m = 1; m <= 32; m <<= 1) l += __shfl_xor(l, m, 64);
      if (lane == 0) atomicAdd(sse, l);
    }
  }
}

// ---------------------------------------------------------------------------
// Kernel 2: EMA update, global n-reduction, normalized embed, loss finalize.
// (unchanged from the verified rounds)
// ---------------------------------------------------------------------------
__global__ __launch_bounds__(1024) void vq_ema(
    const float* __restrict__ counts, const float* __restrict__ sums,
    const float* __restrict__ sse,
    const float* __restrict__ ema_cs, const float* __restrict__ ema_w,
    float* __restrict__ out_loss, float* __restrict__ out_ncs,
    float* __restrict__ out_nw, float* __restrict__ out_nemb)
{
  __shared__ float part[16];
  const int tid = threadIdx.x;
  const float DEC = 0.99f;
  const float OMD = (float)(1.0 - 0.99);
  const float EPS = 1e-5f;

  float ncs[4];
  float nw[12];
  float nsum = 0.0f;

  #pragma unroll
  for (int k = 0; k < 4; ++k) {
    int v = k * 1024 + tid;
    float t = DEC * ema_cs[v] + OMD * counts[v];
    ncs[k] = t;
    out_ncs[v] = t;
    nsum += t;
    #pragma unroll
    for (int d = 0; d < 3; ++d) {
      float w = DEC * ema_w[3 * v + d] + OMD * sums[3 * v + d];
      nw[3 * k + d] = w;
      out_nw[3 * v + d] = w;
    }
  }

  #pragma unroll
  for (int m = 1; m <= 32; m <<= 1) nsum += __shfl_xor(nsum, m, 64);
  if ((tid & 63) == 0) part[tid >> 6] = nsum;
  __syncthreads();

  float n = 0.0f;
  #pragma unroll
  for (int i = 0; i < 16; ++i) n += part[i];
  const float denom = n + (float)VOCAB * EPS;

  #pragma unroll
  for (int k = 0; k < 4; ++k) {
    int v = k * 1024 + tid;
    float cs = (ncs[k] + EPS) / denom * n;
    #pragma unroll
    for (int d = 0; d < 3; ++d)
      out_nemb[3 * v + d] = nw[3 * k + d] / cs;
  }

  if (tid == 0) {
    float m = sse[0] / (float)NELEM;
    out_loss[0] = m + 0.25f * m;   // mean((q-f)^2) + 0.25*mean((f-q)^2)
  }
}

// ---------------------------------------------------------------------------
extern "C" void kernel_launch(void* const* d_in, const int* in_sizes, int n_in,
                              void* d_out, int out_size, void* d_ws, size_t ws_size,
                              hipStream_t stream) {
  const float* feats  = (const float*)d_in[0];   // (4,8192,3)
  const float* embed  = (const float*)d_in[1];   // (4096,3)
  const float* ema_cs = (const float*)d_in[2];   // (4096,)
  const float* ema_w  = (const float*)d_in[3];   // (4096,3)

  float* out      = (float*)d_out;
  float* o_quant  = out;                       // 98304
  float* o_idx    = out + 98304;               // 32768
  float* o_loss   = out + 131072;              // 1
  float* o_ncs    = out + 131073;              // 4096
  float* o_nw     = out + 135169;              // 12288
  float* o_nemb   = out + 147457;              // 12288

  float*  ws_f      = (float*)d_ws;
  float*  ws_counts = ws_f;                    // 4096
  float*  ws_sums   = ws_f + 4096;             // 12288
  float*  ws_sse    = ws_f + 16384;            // 1 (+3 pad)
  float4* ws_pc     = (float4*)(ws_f + 16388); // 4096 float4 (byte 65552, 16B-aligned)

  hipMemsetAsync(d_ws, 0, (size_t)16385 * sizeof(float), stream);

  vq_prep<<<(VOCAB / 2) / 1024, 1024, 0, stream>>>(embed, ws_pc);

  vq_assign<<<NPTS / PTS_PER_BLOCK, BLOCK, VOCAB * sizeof(float4), stream>>>(
      feats, embed, ws_pc, o_quant, o_idx, ws_counts, ws_sums, ws_sse);

  vq_ema<<<1, 1024, 0, stream>>>(
      ws_counts, ws_sums, ws_sse, ema_cs, ema_w,
      o_loss, o_ncs, o_nw, o_nemb);
}

// Round 11
// 50.619 us; speedup vs baseline: 757.7006x; 1.0999x over previous
//
#include <hip/hip_runtime.h>
#include <math.h>

// Disable FP contraction file-wide so every rounding step is the one we wrote;
// fmas are explicit (packed fma asm) matching the XLA/Eigen dot chain.
#pragma clang fp contract(off)

#define VOCAB 4096
#define NPTS  32768          // 4 * 8192
#define NELEM 98304          // NPTS * 3
#define BLOCK 1024
#define NWAVE 16                     // waves per block
#define CPW   (VOCAB / NWAVE)        // 256 codes scanned per wave
#define PAIRS_PW (CPW / 2)           // 128 code-pairs per wave
#define JITER (PAIRS_PW / 2)         // 64 j-iters (1 LDS pair + 1 GLB pair)
#define PPL   2                      // points per lane
#define PTS_PER_BLOCK (64 * PPL)     // 128 points per block -> 256 blocks

typedef float v2f __attribute__((ext_vector_type(2)));

// ---------------------------------------------------------------------------
// Kernel 0: pack codebook in PAIR layout (negated, pre-doubled, + esq) AND
// zero the counts/sums/sse workspace (memset folded in; disjoint buffers, no
// ordering needed).
//   pc[2m]   = (-2e0_k, -2e0_k1, -2e1_k, -2e1_k1)    (codes k=2m, k1=2m+1)
//   pc[2m+1] = (-2e2_k, -2e2_k1,  esq_k,  esq_k1)
// Negation and x2 are exact; IEEE rounding is sign-symmetric, so the packed
// mul/fma chain on these values is bit-exactly -2*dot of the reference chain.
// esq keeps the reference association (e0*e0 + e1*e1) + e2*e2.
// ---------------------------------------------------------------------------
__global__ __launch_bounds__(1024) void vq_prep(
    const float* __restrict__ embed, float4* __restrict__ pc,
    float* __restrict__ wz)
{
  const int gid = blockIdx.x * 1024 + threadIdx.x;   // [0, 2048)
  // zero counts(4096) + sums(12288) = 16384 floats, 8 per thread, + sse
  #pragma unroll
  for (int i = 0; i < 8; ++i) wz[gid * 8 + i] = 0.0f;
  if (gid == 0) wz[16384] = 0.0f;

  const int m = gid;                 // pair id
  const int c0 = 2 * m, c1 = 2 * m + 1;
  float a0 = embed[3 * c0 + 0], a1 = embed[3 * c0 + 1], a2 = embed[3 * c0 + 2];
  float b0 = embed[3 * c1 + 0], b1 = embed[3 * c1 + 1], b2 = embed[3 * c1 + 2];
  float esqa = (a0 * a0 + a1 * a1) + a2 * a2;
  float esqb = (b0 * b0 + b1 * b1) + b2 * b2;
  pc[2 * m + 0] = make_float4(-(a0 + a0), -(b0 + b0), -(a1 + a1), -(b1 + b1));
  pc[2 * m + 1] = make_float4(-(a2 + a2), -(b2 + b2), esqa, esqb);
}

// ---------------------------------------------------------------------------
// Kernel 1: nearest-code assignment + quant_st + idx + scatter + SSE.
//
// r10 post-mortem: LDS-return (10.2us) + VMEM-return (13.7us) + VALU (18.4us)
// SUMMED to the measured 42.8us -- phase-locked waves, nothing in flight
// (VGPR=40). This round keeps the bit-exact packed eval and dual-source
// streams but adds a 4-slot named-register rotating prefetch: loads for
// iteration j+3 issue before compute of iteration j (~260 VALU cycles cover
// LDS ~120 / L2 ~200 latency), so the three pipes overlap -> wall ~= max().
// Also: only even pairs staged to LDS (32 KiB, half the staging), combine
// buffers overlay the dead codebook (0 static LDS).
// Stream k within a wave is ascending in code index; strict < keeps first
// occurrence; lexicographic (d, idx) merges across streams/waves => exact
// argmin first-min semantics (absmax 0 pedigree, r10).
// ---------------------------------------------------------------------------
#define EVALPAIR(P0, P1, C2, ST)                                              \
  {                                                                           \
    v2f A  = {(P0).x, (P0).y};                                                \
    v2f Bv = {(P0).z, (P0).w};                                                \
    v2f Cv = {(P1).x, (P1).y};                                                \
    v2f Sv = {(P1).z, (P1).w};                                                \
    _Pragma("unroll")                                                         \
    for (int s = 0; s < PPL; ++s) {                                           \
      v2f t;                                                                  \
      asm("v_pk_mul_f32 %0, %1, %2" : "=v"(t) : "v"(xp0[s]), "v"(A));         \
      asm("v_pk_fma_f32 %0, %1, %2, %0" : "+v"(t) : "v"(xp1[s]), "v"(Bv));    \
      asm("v_pk_fma_f32 %0, %1, %2, %0" : "+v"(t) : "v"(xp2[s]), "v"(Cv));    \
      asm("v_pk_add_f32 %0, %1, %0" : "+v"(t) : "v"(xpq[s]));                 \
      asm("v_pk_add_f32 %0, %1, %0" : "+v"(t) : "v"(Sv));                     \
      if (t.x < bst[ST][s])     { bst[ST][s] = t.x;     bix[ST][s] = (C2); }  \
      if (t.y < bst[(ST)+1][s]) { bst[(ST)+1][s] = t.y; bix[(ST)+1][s] = (C2) + 1; } \
    }                                                                         \
  }

// lpc holds only EVEN pairs, at their natural float4 index (m0 even =>
// lpc[m0], lpc[m0+1] are that pair's two words; footprint 2048 float4).
#define LOADS(S, jj)                                                          \
  {                                                                           \
    const int m0_ = mbase + 2 * (jj);                                         \
    S##L0 = lpc[m0_];                                                         \
    S##L1 = lpc[m0_ + 1];                                                     \
    S##G0 = gpcv[2 * m0_ + 2];                                                \
    S##G1 = gpcv[2 * m0_ + 3];                                                \
  }

#define COMP(S, jj)                                                           \
  {                                                                           \
    const int c2_ = 2 * (mbase + 2 * (jj));                                   \
    EVALPAIR(S##L0, S##L1, c2_, 0);                                           \
    EVALPAIR(S##G0, S##G1, c2_ + 2, 2);                                       \
  }

__global__ __launch_bounds__(BLOCK, 4) void vq_assign(
    const float* __restrict__ feats, const float* __restrict__ embed,
    const float4* __restrict__ gpc,
    float* __restrict__ out_quant, float* __restrict__ out_idx,
    float* __restrict__ counts, float* __restrict__ sums,
    float* __restrict__ sse)
{
  extern __shared__ float4 lpc[];          // 2048 float4 = 32 KiB

  const int tid  = threadIdx.x;
  const int lane = tid & 63;
  const int wv   = tid >> 6;

  // Stage even pairs: lpc[2ep + w] = gpc[4ep + w], 2 float4 per thread.
  #pragma unroll
  for (int c = tid; c < 2048; c += BLOCK)
    lpc[c] = gpc[4 * (c >> 1) + (c & 1)];
  __syncthreads();

  // Lane owns points pbase+lane (slot 0) and pbase+64+lane (slot 1).
  const int pbase = blockIdx.x * PTS_PER_BLOCK;
  v2f xp0[PPL], xp1[PPL], xp2[PPL], xpq[PPL];
  #pragma unroll
  for (int s = 0; s < PPL; ++s) {
    const int p = pbase + s * 64 + lane;
    float x0 = feats[3 * p + 0];
    float x1 = feats[3 * p + 1];
    float x2 = feats[3 * p + 2];
    float xsq = (x0 * x0 + x1 * x1) + x2 * x2;
    xp0[s] = (v2f){x0, x0}; xp1[s] = (v2f){x1, x1};
    xp2[s] = (v2f){x2, x2}; xpq[s] = (v2f){xsq, xsq};
  }

  // 4 streams per point: 0=LDS-lo, 1=LDS-hi, 2=GLB-lo, 3=GLB-hi
  float bst[4][PPL];
  int   bix[4][PPL];
  #pragma unroll
  for (int st = 0; st < 4; ++st)
    #pragma unroll
    for (int s = 0; s < PPL; ++s) { bst[st][s] = INFINITY; bix[st][s] = 0; }

  // wave's pair range: [mbase, mbase+128); lpc index m0 = mbase+2jj (even
  // since mbase = wv*128). Global stream pair m0+1 via full gpc indexing.
  const int mbase = wv * PAIRS_PW;
  // Opaque VGPR zero: compiler cannot prove uniformity -> vector global
  // loads (L1/L2 path), NOT s_load through the 16KB constant cache (r5 bug).
  int vz;
  asm volatile("v_mov_b32 %0, 0" : "=v"(vz));
  const float4* gpcv = gpc + vz;

  // 4-slot rotating prefetch, named registers only (no runtime indexing).
  float4 aL0, aL1, aG0, aG1;
  float4 bL0, bL1, bG0, bG1;
  float4 cL0, cL1, cG0, cG1;
  float4 dL0, dL1, dG0, dG1;

  LOADS(a, 0); LOADS(b, 1); LOADS(c, 2);
  for (int jb = 0; jb < JITER - 4; jb += 4) {
    LOADS(d, jb + 3); COMP(a, jb);
    LOADS(a, jb + 4); COMP(b, jb + 1);
    LOADS(b, jb + 5); COMP(c, jb + 2);
    LOADS(c, jb + 6); COMP(d, jb + 3);
  }
  LOADS(d, JITER - 1);
  COMP(a, JITER - 4); COMP(b, JITER - 3);
  COMP(c, JITER - 2); COMP(d, JITER - 1);

  // merge the 4 streams per point (lexicographic (d, idx))
  __syncthreads();                         // codebook dead -> overlay OK
  float* dbuf = (float*)lpc;               // [NWAVE][PPL][64] floats (8 KiB)
  int*   ibuf = (int*)lpc + NWAVE * PPL * 64;
  #pragma unroll
  for (int s = 0; s < PPL; ++s) {
    float b = bst[0][s];
    int   bi = bix[0][s];
    #pragma unroll
    for (int st = 1; st < 4; ++st) {
      if (bst[st][s] < b || (bst[st][s] == b && bix[st][s] < bi)) {
        b = bst[st][s]; bi = bix[st][s];
      }
    }
    dbuf[(wv * PPL + s) * 64 + lane] = b;
    ibuf[(wv * PPL + s) * 64 + lane] = bi;
  }
  __syncthreads();

  if (wv == 0) {
    #pragma unroll
    for (int s = 0; s < PPL; ++s) {
      float b = dbuf[s * 64 + lane];
      int   bi = ibuf[s * 64 + lane];
      #pragma unroll
      for (int w = 1; w < NWAVE; ++w) {
        float od = dbuf[(w * PPL + s) * 64 + lane];
        int   oi = ibuf[(w * PPL + s) * 64 + lane];
        // lexicographic (d, idx): wave ranges ascending => first-min
        if (od < b || (od == b && oi < bi)) { b = od; bi = oi; }
      }

      const int p = pbase + s * 64 + lane;
      // winning code values straight from embed: bit-exact originals
      const float q0 = embed[3 * bi + 0];
      const float q1 = embed[3 * bi + 1];
      const float q2 = embed[3 * bi + 2];
      const float x0 = xp0[s].x, x1 = xp1[s].x, x2 = xp2[s].x;

      // quant_st = feats + (quant - feats), exactly as the reference does
      out_quant[3 * p + 0] = x0 + (q0 - x0);
      out_quant[3 * p + 1] = x1 + (q1 - x1);
      out_quant[3 * p + 2] = x2 + (q2 - x2);
      out_idx[p] = (float)bi;

      atomicAdd(&counts[bi], 1.0f);
      atomicAdd(&sums[3 * bi + 0], x0);
      atomicAdd(&sums[3 * bi + 1], x1);
      atomicAdd(&sums[3 * bi + 2], x2);

      float d0 = q0 - x0, d1 = q1 - x1, d2 = q2 - x2;
      float l = (d0 * d0 + d1 * d1) + d2 * d2;
      #pragma unroll
      for (int m = 1; m <= 32; m <<= 1) l += __shfl_xor(l, m, 64);
      if (lane == 0) atomicAdd(sse, l);
    }
  }
}

// ---------------------------------------------------------------------------
// Kernel 2: EMA update, global n-reduction, normalized embed, loss finalize.
// (unchanged from the verified rounds)
// ---------------------------------------------------------------------------
__global__ __launch_bounds__(1024) void vq_ema(
    const float* __restrict__ counts, const float* __restrict__ sums,
    const float* __restrict__ sse,
    const float* __restrict__ ema_cs, const float* __restrict__ ema_w,
    float* __restrict__ out_loss, float* __restrict__ out_ncs,
    float* __restrict__ out_nw, float* __restrict__ out_nemb)
{
  __shared__ float part[16];
  const int tid = threadIdx.x;
  const float DEC = 0.99f;
  const float OMD = (float)(1.0 - 0.99);
  const float EPS = 1e-5f;

  float ncs[4];
  float nw[12];
  float nsum = 0.0f;

  #pragma unroll
  for (int k = 0; k < 4; ++k) {
    int v = k * 1024 + tid;
    float t = DEC * ema_cs[v] + OMD * counts[v];
    ncs[k] = t;
    out_ncs[v] = t;
    nsum += t;
    #pragma unroll
    for (int d = 0; d < 3; ++d) {
      float w = DEC * ema_w[3 * v + d] + OMD * sums[3 * v + d];
      nw[3 * k + d] = w;
      out_nw[3 * v + d] = w;
    }
  }

  #pragma unroll
  for (int m = 1; m <= 32; m <<= 1) nsum += __shfl_xor(nsum, m, 64);
  if ((tid & 63) == 0) part[tid >> 6] = nsum;
  __syncthreads();

  float n = 0.0f;
  #pragma unroll
  for (int i = 0; i < 16; ++i) n += part[i];
  const float denom = n + (float)VOCAB * EPS;

  #pragma unroll
  for (int k = 0; k < 4; ++k) {
    int v = k * 1024 + tid;
    float cs = (ncs[k] + EPS) / denom * n;
    #pragma unroll
    for (int d = 0; d < 3; ++d)
      out_nemb[3 * v + d] = nw[3 * k + d] / cs;
  }

  if (tid == 0) {
    float m = sse[0] / (float)NELEM;
    out_loss[0] = m + 0.25f * m;   // mean((q-f)^2) + 0.25*mean((f-q)^2)
  }
}

// ---------------------------------------------------------------------------
extern "C" void kernel_launch(void* const* d_in, const int* in_sizes, int n_in,
                              void* d_out, int out_size, void* d_ws, size_t ws_size,
                              hipStream_t stream) {
  const float* feats  = (const float*)d_in[0];   // (4,8192,3)
  const float* embed  = (const float*)d_in[1];   // (4096,3)
  const float* ema_cs = (const float*)d_in[2];   // (4096,)
  const float* ema_w  = (const float*)d_in[3];   // (4096,3)

  float* out      = (float*)d_out;
  float* o_quant  = out;                       // 98304
  float* o_idx    = out + 98304;               // 32768
  float* o_loss   = out + 131072;              // 1
  float* o_ncs    = out + 131073;              // 4096
  float* o_nw     = out + 135169;              // 12288
  float* o_nemb   = out + 147457;              // 12288

  float*  ws_f      = (float*)d_ws;
  float*  ws_counts = ws_f;                    // 4096
  float*  ws_sums   = ws_f + 4096;             // 12288
  float*  ws_sse    = ws_f + 16384;            // 1 (+3 pad)
  float4* ws_pc     = (float4*)(ws_f + 16388); // 4096 float4 (byte 65552, 16B-aligned)

  vq_prep<<<2, 1024, 0, stream>>>(embed, ws_pc, ws_f);

  vq_assign<<<NPTS / PTS_PER_BLOCK, BLOCK, 2048 * sizeof(float4), stream>>>(
      feats, embed, ws_pc, o_quant, o_idx, ws_counts, ws_sums, ws_sse);

  vq_ema<<<1, 1024, 0, stream>>>(
      ws_counts, ws_sums, ws_sse, ema_cs, ema_w,
      o_loss, o_ncs, o_nw, o_nemb);
}